// Round 3
// baseline (265.364 us; speedup 1.0000x reference)
//
#include <hip/hip_runtime.h>
#include <cmath>

// BKT forward, B independent students, serial T-step fp32 recurrence.
//
// NUMERICS (R1/R2 lesson): the harness validates against an fp32 numpy
// recompute ("ref=np"). The recurrence amplifies rounding ~2e5x over 512
// steps: fp64 truth drifts 0.0234 from the fp32 reference (> 0.02 thresh).
// The only way to pass is to CORRELATE with the reference's roundings:
//  - exact numpy op order, separate IEEE fp32 mul/add/div (NO FMA - pragma)
//  - sigmoid params computed in fp64, rounded once to fp32 (<=1 ulp from
//    numpy's fp32 sigmoid; same divergence class as JAX's passing fp32 run)
//  - select num/den then divide == compute k_t1,k_t0 and select (bit-equal)
__global__ __launch_bounds__(256) void bkt_fwd(
    const int* __restrict__ X,          // (B,4) int32 indices
    const int* __restrict__ Y,          // (B,T) int32 observations {0,1}
    const float* __restrict__ learn_w,  // (N,1)
    const float* __restrict__ guess_w,
    const float* __restrict__ slip_w,
    const float* __restrict__ prior_w,
    float* __restrict__ out,            // corrects (B,T) then latents (B,T)
    int B, int T)
{
#pragma clang fp contract(off)
    const int b = blockIdx.x * blockDim.x + threadIdx.x;
    if (b >= B) return;

    const int4 xi = *reinterpret_cast<const int4*>(X + (size_t)b * 4);
    // correctly-rounded fp32 sigmoids via fp64
    const float l = (float)(1.0 / (1.0 + exp(-(double)learn_w[xi.x])));
    const float g = (float)(1.0 / (1.0 + exp(-(double)guess_w[xi.y])));
    const float s = (float)(1.0 / (1.0 + exp(-(double)slip_w[xi.z])));
    const float p = (float)(1.0 / (1.0 + exp(-(double)prior_w[xi.w])));

    const float oms = 1.0f - s;              // (1-s), rounded once like np
    const float omg = 1.0f - g;              // (1-g)
    const float lo  = 1e-6f;                 // EPS
    const float hi  = (float)(1.0 - 1e-6);   // fp32(1 - EPS) as np computes it

    float latent = p;

    const int4* __restrict__ yv = reinterpret_cast<const int4*>(Y + (size_t)b * T);
    float4* __restrict__ co = reinterpret_cast<float4*>(out + (size_t)b * T);
    float4* __restrict__ la = reinterpret_cast<float4*>(out + (size_t)B * T + (size_t)b * T);

    const int nT4 = T >> 2;
    for (int tt = 0; tt < nT4; ++tt) {
        const int4 yq = yv[tt];   // 4 timesteps of y, independent of the chain
        const int yy[4] = {yq.x, yq.y, yq.z, yq.w};
        float cr[4], lt[4];
        #pragma unroll
        for (int j = 0; j < 4; ++j) {
            // every statement = one IEEE fp32 rounding, np's association order
            const float a      = latent * oms;        // latent*(1-s)
            const float omlat  = 1.0f - latent;       // (1-latent)
            const float t1     = omlat * g;           // (1-latent)*g
            const float correct = a + t1;             // rounded add
            const float n0     = latent * s;          // latent*s
            const float t2     = omlat * omg;         // (1-latent)*(1-g)
            const float d0     = n0 + t2;             // rounded add
            const bool hit = yy[j] > 0;               // y_t > 0.5
            const float num = hit ? a : n0;
            const float den = hit ? correct : d0;
            const float k   = num / den;              // IEEE fp32 divide
            cr[j] = correct;
            lt[j] = latent;                           // recorded BEFORE update
            const float omk = 1.0f - k;               // (1-k)
            const float t3  = omk * l;                // (1-k)*l
            const float nxt = k + t3;                 // rounded add
            latent = fminf(fmaxf(nxt, lo), hi);       // clip
        }
        co[tt] = make_float4(cr[0], cr[1], cr[2], cr[3]);
        la[tt] = make_float4(lt[0], lt[1], lt[2], lt[3]);
    }
}

extern "C" void kernel_launch(void* const* d_in, const int* in_sizes, int n_in,
                              void* d_out, int out_size, void* d_ws, size_t ws_size,
                              hipStream_t stream)
{
    const int*   X  = (const int*)d_in[0];
    const int*   Y  = (const int*)d_in[1];
    const float* lw = (const float*)d_in[2];
    const float* gw = (const float*)d_in[3];
    const float* sw = (const float*)d_in[4];
    const float* pw = (const float*)d_in[5];
    float* out = (float*)d_out;

    const int B = in_sizes[0] / 4;
    const int T = in_sizes[1] / B;   // 512

    const int threads = 256;
    const int blocks = (B + threads - 1) / threads;
    bkt_fwd<<<blocks, threads, 0, stream>>>(X, Y, lw, gw, sw, pw, out, B, T);
}

// Round 4
// 152.936 us; speedup vs baseline: 1.7351x; 1.7351x over previous
//
#include <hip/hip_runtime.h>
#include <cmath>

// BKT forward, B independent students, serial T-step fp32 recurrence.
//
// NUMERICS (R1-R3): harness validates vs fp32 numpy recompute; recurrence
// amplifies rounding ~2e5x over 512 steps -> must replicate np's fp32 op
// order exactly (no FMA contraction, separate rounded mul/add/div, fp64
// sigmoid rounded once). R3 passed with absmax 0.0039. DO NOT reassociate.
//
// PERF (R3 rocprof): WRITE_SIZE was 1.05 GB vs 268 MB ideal (3.9x = 64B
// flushed per 16B store: the 4 stores filling a sector were ~1000cy apart).
// Fix: buffer 32 timesteps in registers, store 8x float4 back-to-back per
// stream -> full 128B chunks written temporally together. Grid-limited
// occupancy (1 wave/SIMD) makes the extra ~70 VGPR free.

__device__ __forceinline__ int comp4(const int4& v, int c) {
    return c == 0 ? v.x : c == 1 ? v.y : c == 2 ? v.z : v.w;
}

__global__ __launch_bounds__(256) void bkt_fwd(
    const int* __restrict__ X,          // (B,4) int32 indices
    const int* __restrict__ Y,          // (B,T) int32 observations {0,1}
    const float* __restrict__ learn_w,  // (N,1)
    const float* __restrict__ guess_w,
    const float* __restrict__ slip_w,
    const float* __restrict__ prior_w,
    float* __restrict__ out,            // corrects (B,T) then latents (B,T)
    int B, int T)
{
#pragma clang fp contract(off)
    const int b = blockIdx.x * blockDim.x + threadIdx.x;
    if (b >= B) return;

    const int4 xi = *reinterpret_cast<const int4*>(X + (size_t)b * 4);
    // correctly-rounded fp32 sigmoids via fp64
    const float l = (float)(1.0 / (1.0 + exp(-(double)learn_w[xi.x])));
    const float g = (float)(1.0 / (1.0 + exp(-(double)guess_w[xi.y])));
    const float s = (float)(1.0 / (1.0 + exp(-(double)slip_w[xi.z])));
    const float p = (float)(1.0 / (1.0 + exp(-(double)prior_w[xi.w])));

    const float oms = 1.0f - s;              // (1-s), rounded once like np
    const float omg = 1.0f - g;              // (1-g)
    const float lo  = 1e-6f;
    const float hi  = (float)(1.0 - 1e-6);   // fp32(1-EPS)

    float latent = p;

    const int4*  __restrict__ yv = reinterpret_cast<const int4*>(Y + (size_t)b * T);
    float4* __restrict__ co = reinterpret_cast<float4*>(out + (size_t)b * T);
    float4* __restrict__ la = reinterpret_cast<float4*>(out + (size_t)B * T + (size_t)b * T);

    constexpr int STEPS = 32;                // timesteps buffered per outer iter
    const int nOuter = T / STEPS;            // 16
    for (int o = 0; o < nOuter; ++o) {
        // batch the 32 y values (128B contiguous, independent of the chain)
        int4 yq[STEPS / 4];
        #pragma unroll
        for (int q = 0; q < STEPS / 4; ++q) yq[q] = yv[o * (STEPS / 4) + q];

        float cr[STEPS], lt[STEPS];
        #pragma unroll
        for (int j = 0; j < STEPS; ++j) {    // fully unrolled: static indexing
            // every statement = one IEEE fp32 rounding, np's association order
            const float a       = latent * oms;       // latent*(1-s)
            const float omlat   = 1.0f - latent;      // (1-latent)
            const float t1      = omlat * g;          // (1-latent)*g
            const float correct = a + t1;
            const float n0      = latent * s;         // latent*s
            const float t2      = omlat * omg;        // (1-latent)*(1-g)
            const float d0      = n0 + t2;
            const bool hit = comp4(yq[j >> 2], j & 3) > 0;   // y_t > 0.5
            const float num = hit ? a : n0;
            const float den = hit ? correct : d0;
            const float k   = num / den;              // IEEE fp32 divide
            cr[j] = correct;
            lt[j] = latent;                           // recorded BEFORE update
            const float omk = 1.0f - k;
            const float t3  = omk * l;                // (1-k)*l
            const float nxt = k + t3;                 // k + (1-k)*l
            latent = fminf(fmaxf(nxt, lo), hi);       // clip
        }

        // back-to-back 128B-per-stream stores: sectors complete before eviction
        float4* __restrict__ cop = co + o * (STEPS / 4);
        float4* __restrict__ lap = la + o * (STEPS / 4);
        #pragma unroll
        for (int q = 0; q < STEPS / 4; ++q)
            cop[q] = make_float4(cr[4*q], cr[4*q+1], cr[4*q+2], cr[4*q+3]);
        #pragma unroll
        for (int q = 0; q < STEPS / 4; ++q)
            lap[q] = make_float4(lt[4*q], lt[4*q+1], lt[4*q+2], lt[4*q+3]);
    }
}

extern "C" void kernel_launch(void* const* d_in, const int* in_sizes, int n_in,
                              void* d_out, int out_size, void* d_ws, size_t ws_size,
                              hipStream_t stream)
{
    const int*   X  = (const int*)d_in[0];
    const int*   Y  = (const int*)d_in[1];
    const float* lw = (const float*)d_in[2];
    const float* gw = (const float*)d_in[3];
    const float* sw = (const float*)d_in[4];
    const float* pw = (const float*)d_in[5];
    float* out = (float*)d_out;

    const int B = in_sizes[0] / 4;
    const int T = in_sizes[1] / B;   // 512

    const int threads = 256;
    const int blocks = (B + threads - 1) / threads;
    bkt_fwd<<<blocks, threads, 0, stream>>>(X, Y, lw, gw, sw, pw, out, B, T);
}

// Round 5
// 122.094 us; speedup vs baseline: 2.1734x; 1.2526x over previous
//
#include <hip/hip_runtime.h>
#include <cmath>

// BKT forward, B independent students, serial T-step fp32 recurrence.
//
// NUMERICS (R1-R3): harness validates vs fp32 numpy recompute; recurrence
// amplifies rounding ~2e5x over 512 steps -> must replicate np's fp32 op
// order exactly (no FMA contraction, separate rounded mul/add/div, fp64
// sigmoid rounded once). R3/R4 passed with absmax 0.0039. DO NOT reassociate.
//
// PERF (R4 rocprof): WRITE_SIZE 437 MB vs 268 MB ideal (1.63x). VGPR=32
// proves the compiler SANK the buffered stores back into the compute loop
// to hit a default occupancy target we can't use (grid = 65536 thr = 1
// wave/SIMD, grid-limited). Fix: __launch_bounds__(256, 1) -> register
// budget 512, cr/lt stay live, 8+8 back-to-back global_store_dwordx4 per
// outer iter -> sectors fill within ~50cy -> full-line HBM writes.
// Also: software-pipeline y-loads (preload o+1) since 1 wave/SIMD = no TLP.

__device__ __forceinline__ int comp4(const int4& v, int c) {
    return c == 0 ? v.x : c == 1 ? v.y : c == 2 ? v.z : v.w;
}

__global__ __launch_bounds__(256, 1) void bkt_fwd(
    const int* __restrict__ X,          // (B,4) int32 indices
    const int* __restrict__ Y,          // (B,T) int32 observations {0,1}
    const float* __restrict__ learn_w,  // (N,1)
    const float* __restrict__ guess_w,
    const float* __restrict__ slip_w,
    const float* __restrict__ prior_w,
    float* __restrict__ out,            // corrects (B,T) then latents (B,T)
    int B, int T)
{
#pragma clang fp contract(off)
    const int b = blockIdx.x * blockDim.x + threadIdx.x;
    if (b >= B) return;

    const int4 xi = *reinterpret_cast<const int4*>(X + (size_t)b * 4);
    // correctly-rounded fp32 sigmoids via fp64
    const float l = (float)(1.0 / (1.0 + exp(-(double)learn_w[xi.x])));
    const float g = (float)(1.0 / (1.0 + exp(-(double)guess_w[xi.y])));
    const float s = (float)(1.0 / (1.0 + exp(-(double)slip_w[xi.z])));
    const float p = (float)(1.0 / (1.0 + exp(-(double)prior_w[xi.w])));

    const float oms = 1.0f - s;              // (1-s), rounded once like np
    const float omg = 1.0f - g;              // (1-g)
    const float lo  = 1e-6f;
    const float hi  = (float)(1.0 - 1e-6);   // fp32(1-EPS)

    float latent = p;

    const int4*  __restrict__ yv = reinterpret_cast<const int4*>(Y + (size_t)b * T);
    float4* __restrict__ co = reinterpret_cast<float4*>(out + (size_t)b * T);
    float4* __restrict__ la = reinterpret_cast<float4*>(out + (size_t)B * T + (size_t)b * T);

    constexpr int STEPS = 32;                // timesteps buffered per outer iter
    constexpr int NQ = STEPS / 4;            // 8 int4/float4 per chunk
    const int nOuter = T / STEPS;            // 16

    // software pipeline: preload y chunk for o=0
    int4 yq[NQ], yqn[NQ];
    #pragma unroll
    for (int q = 0; q < NQ; ++q) yq[q] = yv[q];

    for (int o = 0; o < nOuter; ++o) {
        // issue next chunk's y loads early; latency hides under compute
        if (o + 1 < nOuter) {
            #pragma unroll
            for (int q = 0; q < NQ; ++q) yqn[q] = yv[(o + 1) * NQ + q];
        }

        float cr[STEPS], lt[STEPS];
        #pragma unroll
        for (int j = 0; j < STEPS; ++j) {    // fully unrolled: static indexing
            // every statement = one IEEE fp32 rounding, np's association order
            const float a       = latent * oms;       // latent*(1-s)
            const float omlat   = 1.0f - latent;      // (1-latent)
            const float t1      = omlat * g;          // (1-latent)*g
            const float correct = a + t1;
            const float n0      = latent * s;         // latent*s
            const float t2      = omlat * omg;        // (1-latent)*(1-g)
            const float d0      = n0 + t2;
            const bool hit = comp4(yq[j >> 2], j & 3) > 0;   // y_t > 0.5
            const float num = hit ? a : n0;
            const float den = hit ? correct : d0;
            const float k   = num / den;              // IEEE fp32 divide
            cr[j] = correct;
            lt[j] = latent;                           // recorded BEFORE update
            const float omk = 1.0f - k;
            const float t3  = omk * l;                // (1-k)*l
            const float nxt = k + t3;                 // k + (1-k)*l
            latent = fminf(fmaxf(nxt, lo), hi);       // clip
        }

        // back-to-back 128B-per-stream store bursts: full-line HBM writes
        float4* __restrict__ cop = co + o * NQ;
        float4* __restrict__ lap = la + o * NQ;
        #pragma unroll
        for (int q = 0; q < NQ; ++q)
            cop[q] = make_float4(cr[4*q], cr[4*q+1], cr[4*q+2], cr[4*q+3]);
        #pragma unroll
        for (int q = 0; q < NQ; ++q)
            lap[q] = make_float4(lt[4*q], lt[4*q+1], lt[4*q+2], lt[4*q+3]);

        #pragma unroll
        for (int q = 0; q < NQ; ++q) yq[q] = yqn[q];
    }
}

extern "C" void kernel_launch(void* const* d_in, const int* in_sizes, int n_in,
                              void* d_out, int out_size, void* d_ws, size_t ws_size,
                              hipStream_t stream)
{
    const int*   X  = (const int*)d_in[0];
    const int*   Y  = (const int*)d_in[1];
    const float* lw = (const float*)d_in[2];
    const float* gw = (const float*)d_in[3];
    const float* sw = (const float*)d_in[4];
    const float* pw = (const float*)d_in[5];
    float* out = (float*)d_out;

    const int B = in_sizes[0] / 4;
    const int T = in_sizes[1] / B;   // 512

    const int threads = 256;
    const int blocks = (B + threads - 1) / threads;
    bkt_fwd<<<blocks, threads, 0, stream>>>(X, Y, lw, gw, sw, pw, out, B, T);
}

// Round 6
// 89.978 us; speedup vs baseline: 2.9492x; 1.3569x over previous
//
#include <hip/hip_runtime.h>
#include <cmath>

// BKT forward, B independent students, serial T-step fp32 recurrence.
//
// NUMERICS (R1-R3): harness validates vs fp32 numpy recompute; recurrence
// amplifies rounding ~2e5x over 512 steps -> must replicate np's fp32 op
// order exactly (no FMA contraction, separate rounded mul/add/div, fp64
// sigmoid rounded once). Passing absmax = 0.0039. DO NOT reassociate.
//
// PERF history:
//  R3: per-step scattered stores -> WRITE 1.05 GB (3.9x), 268 us
//  R4: reg-buffered stores, compiler sank them (VGPR=32) -> 437 MB, 153 us
//  R5: __launch_bounds__(256,1) freed regs -> 122 us, but each wave64 store
//      still touches 64 distinct 128B lines at 16 B/txn (lane-stride 2048B).
//  R6 (this): LDS-transpose store phase: one store instr = 8 rows x full
//      128B line (8 lanes cover one row's 32-float chunk) -> 8 txns of 128B
//      per instr, zero partial sectors by construction. Wave-private LDS
//      tile (each wave reads only its own 64 threads' rows) -> no
//      __syncthreads; wave_barrier pins compiler ordering (same-wave DS ops
//      are processed in order by the LDS pipe).

#define LSTR 36   // LDS row stride in floats: 144 B = 16B-aligned, b128 ops at 2-way floor

__device__ __forceinline__ int comp4(const int4& v, int c) {
    return c == 0 ? v.x : c == 1 ? v.y : c == 2 ? v.z : v.w;
}

__global__ __launch_bounds__(256, 1) void bkt_fwd(
    const int* __restrict__ X,          // (B,4) int32 indices
    const int* __restrict__ Y,          // (B,T) int32 observations {0,1}
    const float* __restrict__ learn_w,  // (N,1)
    const float* __restrict__ guess_w,
    const float* __restrict__ slip_w,
    const float* __restrict__ prior_w,
    float* __restrict__ out,            // corrects (B,T) then latents (B,T)
    int B, int T)                       // requires B % 256 == 0 (65536 ok)
{
#pragma clang fp contract(off)
    const int tid = threadIdx.x;
    const int b = blockIdx.x * 256 + tid;

    __shared__ float xp[256 * LSTR];    // 36.9 KB, reused cr-pass then lt-pass

    const int4 xi = *reinterpret_cast<const int4*>(X + (size_t)b * 4);
    // correctly-rounded fp32 sigmoids via fp64
    const float l = (float)(1.0 / (1.0 + exp(-(double)learn_w[xi.x])));
    const float g = (float)(1.0 / (1.0 + exp(-(double)guess_w[xi.y])));
    const float s = (float)(1.0 / (1.0 + exp(-(double)slip_w[xi.z])));
    const float p = (float)(1.0 / (1.0 + exp(-(double)prior_w[xi.w])));

    const float oms = 1.0f - s;              // (1-s)
    const float omg = 1.0f - g;              // (1-g)
    const float lo  = 1e-6f;
    const float hi  = (float)(1.0 - 1e-6);   // fp32(1-EPS)
    float latent = p;

    const int4* __restrict__ yv = reinterpret_cast<const int4*>(Y + (size_t)b * T);

    // store-phase lane mapping: instr q covers rows (wv*64 + q*8 + r8),
    // 8 lanes per row, lane's 16B sub-chunk at col c8*4.
    const int wv = tid >> 6, ln = tid & 63;
    const int r8 = ln >> 3, c8 = ln & 7;
    float* __restrict__ lrow = xp + tid * LSTR;                       // my write row
    const float* __restrict__ lrd = xp + (wv * 64 + r8) * LSTR + c8 * 4; // read base
    float* __restrict__ gco = out + (size_t)(blockIdx.x * 256 + wv * 64 + r8) * T + c8 * 4;
    float* __restrict__ gla = gco + (size_t)B * T;

    constexpr int STEPS = 32, NQ = 8;
    const int nOuter = T / STEPS;            // 16

    // software pipeline: preload y chunk for o=0 (1 wave/SIMD -> no TLP)
    int4 yq[NQ], yqn[NQ];
    #pragma unroll
    for (int q = 0; q < NQ; ++q) yq[q] = yv[q];

    for (int o = 0; o < nOuter; ++o) {
        if (o + 1 < nOuter) {
            #pragma unroll
            for (int q = 0; q < NQ; ++q) yqn[q] = yv[(o + 1) * NQ + q];
        }

        float cr[STEPS], lt[STEPS];
        #pragma unroll
        for (int j = 0; j < STEPS; ++j) {    // fully unrolled: static indexing
            // every statement = one IEEE fp32 rounding, np's association order
            const float a       = latent * oms;       // latent*(1-s)
            const float omlat   = 1.0f - latent;      // (1-latent)
            const float t1      = omlat * g;          // (1-latent)*g
            const float correct = a + t1;
            const float n0      = latent * s;         // latent*s
            const float t2      = omlat * omg;        // (1-latent)*(1-g)
            const float d0      = n0 + t2;
            const bool hit = comp4(yq[j >> 2], j & 3) > 0;   // y_t > 0.5
            const float num = hit ? a : n0;
            const float den = hit ? correct : d0;
            const float k   = num / den;              // IEEE fp32 divide
            cr[j] = correct;
            lt[j] = latent;                           // recorded BEFORE update
            const float omk = 1.0f - k;
            const float t3  = omk * l;                // (1-k)*l
            const float nxt = k + t3;                 // k + (1-k)*l
            latent = fminf(fmaxf(nxt, lo), hi);       // clip
        }

        const int colo = o * STEPS;

        // ---- corrects: regs -> LDS row -> dense full-line global stores ----
        #pragma unroll
        for (int q = 0; q < NQ; ++q)
            *reinterpret_cast<float4*>(lrow + q * 4) =
                make_float4(cr[4*q], cr[4*q+1], cr[4*q+2], cr[4*q+3]);
        __builtin_amdgcn_wave_barrier();   // order ds_write before ds_read
        #pragma unroll
        for (int q = 0; q < NQ; ++q) {
            const float4 v = *reinterpret_cast<const float4*>(lrd + (q * 8) * LSTR);
            *reinterpret_cast<float4*>(gco + (size_t)(q * 8) * T + colo) = v;
        }
        __builtin_amdgcn_wave_barrier();   // order reads before lt-pass overwrite

        // ---- latents ----
        #pragma unroll
        for (int q = 0; q < NQ; ++q)
            *reinterpret_cast<float4*>(lrow + q * 4) =
                make_float4(lt[4*q], lt[4*q+1], lt[4*q+2], lt[4*q+3]);
        __builtin_amdgcn_wave_barrier();
        #pragma unroll
        for (int q = 0; q < NQ; ++q) {
            const float4 v = *reinterpret_cast<const float4*>(lrd + (q * 8) * LSTR);
            *reinterpret_cast<float4*>(gla + (size_t)(q * 8) * T + colo) = v;
        }
        __builtin_amdgcn_wave_barrier();

        #pragma unroll
        for (int q = 0; q < NQ; ++q) yq[q] = yqn[q];
    }
}

extern "C" void kernel_launch(void* const* d_in, const int* in_sizes, int n_in,
                              void* d_out, int out_size, void* d_ws, size_t ws_size,
                              hipStream_t stream)
{
    const int*   X  = (const int*)d_in[0];
    const int*   Y  = (const int*)d_in[1];
    const float* lw = (const float*)d_in[2];
    const float* gw = (const float*)d_in[3];
    const float* sw = (const float*)d_in[4];
    const float* pw = (const float*)d_in[5];
    float* out = (float*)d_out;

    const int B = in_sizes[0] / 4;   // 65536
    const int T = in_sizes[1] / B;   // 512

    const int threads = 256;
    const int blocks = B / threads;  // B % 256 == 0
    bkt_fwd<<<blocks, threads, 0, stream>>>(X, Y, lw, gw, sw, pw, out, B, T);
}